// Round 1
// baseline (155.438 us; speedup 1.0000x reference)
//
#include <hip/hip_runtime.h>

#define B_SZ 1024
#define F_SZ 32
#define D_SZ 128
#define FD   (F_SZ * D_SZ)      // 4096 shorts/floats per b-row of feature
#define NPAIR 496               // F*(F-1)/2

typedef __bf16 bf16x8 __attribute__((ext_vector_type(8)));
typedef float floatx4 __attribute__((ext_vector_type(4)));
typedef unsigned short u16x4 __attribute__((ext_vector_type(4)));
typedef unsigned short u16x8 __attribute__((ext_vector_type(8)));

__device__ __forceinline__ unsigned short f2bf(float f) {
  // round-to-nearest-even fp32 -> bf16 (no NaN inputs here)
  unsigned u = __float_as_uint(f);
  u += 0x7fffu + ((u >> 16) & 1u);
  return (unsigned short)(u >> 16);
}

__device__ __forceinline__ void gload_lds16(const void* g, void* l) {
  // async 16B/lane global->LDS; LDS dest = wave-uniform base + lane*16
  __builtin_amdgcn_global_load_lds(
      (const __attribute__((address_space(1))) unsigned int*)g,
      (__attribute__((address_space(3))) unsigned int*)l,
      16, 0, 0);
}

// ---------- pre-pass A: feature fp32 -> bf16, same [B][F][D] layout ----------
__global__ void feat_cvt_kernel(const float* __restrict__ feat,
                                unsigned short* __restrict__ featB) {
  const int idx8 = blockIdx.x * 256 + threadIdx.x;   // 524288 groups of 8
  const float4* f4 = (const float4*)feat;
  const float4 v0 = f4[(size_t)idx8 * 2];
  const float4 v1 = f4[(size_t)idx8 * 2 + 1];
  u16x8 h;
  h[0] = f2bf(v0.x); h[1] = f2bf(v0.y); h[2] = f2bf(v0.z); h[3] = f2bf(v0.w);
  h[4] = f2bf(v1.x); h[5] = f2bf(v1.y); h[6] = f2bf(v1.z); h[7] = f2bf(v1.w);
  *(u16x8*)&featB[(size_t)idx8 * 8] = h;
}

// ---------- pre-pass B: Z -> sigmoid/stretch/clip -> bf16, transposed [e][d],
// XOR-swizzled in 8-short groups: group g stored at g ^ (e&7) (for bank-free
// ds_read_b128 of B-frags after a LINEAR global_load_lds stage) ----------
__global__ void z_prep_kernel(const float* __restrict__ mat,
                              unsigned short* __restrict__ ZT) {
  __shared__ unsigned short tr[128 * 132];   // [e][d], pad to 132 shorts/row
  const int t = threadIdx.x;

  int p = blockIdx.x, i = 0;
  while (p >= F_SZ - 1 - i) { p -= F_SZ - 1 - i; ++i; }
  const int j = i + 1 + p;

  const float* zp = mat + (((size_t)i * F_SZ + j) * (size_t)(D_SZ * D_SZ));
  #pragma unroll 4
  for (int it = 0; it < 16; ++it) {
    int idx4 = it * 256 + t;                 // [0,4096) float4 groups
    int d = idx4 >> 5, e4 = (idx4 & 31) * 4; // coalesced along e
    const float4 v = *(const float4*)(zp + d * D_SZ + e4);
    float zs[4] = {v.x, v.y, v.z, v.w};
    #pragma unroll
    for (int c = 0; c < 4; ++c) {
      float s = 1.0f / (1.0f + __expf(-zs[c]));
      float z = fminf(1.0f, fmaxf(0.0f, fmaf(s, 1.2f, -0.1f)));
      tr[(e4 + c) * 132 + d] = f2bf(z);      // transposed store
    }
  }
  __syncthreads();

  unsigned short* zo = ZT + (size_t)blockIdx.x * (D_SZ * D_SZ);
  #pragma unroll 2
  for (int it = 0; it < 8; ++it) {
    int G = it * 256 + t;                    // [0,2048): (e, out-group)
    int e = G >> 4, gp = G & 15;
    int g = gp ^ (e & 7);                    // swizzle: out group gp holds src group g
    u16x4 lo = *(const u16x4*)&tr[e * 132 + g * 8];
    u16x4 hi = *(const u16x4*)&tr[e * 132 + g * 8 + 4];
    *(u16x4*)&zo[e * 128 + gp * 8]     = lo; // coalesced global store
    *(u16x4*)&zo[e * 128 + gp * 8 + 4] = hi;
  }
}

// ---------- main: one block per (pair, b-split of 256 rows), 4 waves ----------
// sZ staged once (linear global_load_lds, content pre-swizzled), Z B-frags held
// in 128 VGPRs per wave for the whole block; A-frags straight from global bf16.
// ONE barrier per block; tile loop is barrier-free.
__global__ __launch_bounds__(256, 2)
void interaction_pair_kernel(const float* __restrict__ feat,
                             const unsigned short* __restrict__ featB,
                             const unsigned short* __restrict__ ZT,
                             float* __restrict__ out) {
  __shared__ unsigned short sZ[128 * 128];   // 32KB, swizzled [e][d']

  const int t    = threadIdx.x;
  const int w    = t >> 6;
  const int lane = t & 63;
  const int l15  = lane & 15;
  const int quad = lane >> 4;

  const int pid   = blockIdx.x >> 2;
  const int split = blockIdx.x & 3;
  int p = pid, i = 0;
  while (p >= F_SZ - 1 - i) { p -= F_SZ - 1 - i; ++i; }
  const int j = i + 1 + p;

  // ---- stage sZ: 32KB linear async copy (8 x 1KB per wave) ----
  {
    const char* src = (const char*)(ZT + (size_t)pid * (D_SZ * D_SZ));
    #pragma unroll
    for (int it = 0; it < 8; ++it) {
      int off = it * 4096 + w * 1024;        // wave-uniform LDS offset
      gload_lds16(src + off + lane * 16, (char*)sZ + off);
    }
  }
  __syncthreads();   // drains vmcnt -> sZ valid; the ONLY barrier

  // ---- Z B-frags -> registers, once per block (swizzled LDS reads) ----
  bf16x8 zfr[4][8];  // [k-step][nf]; 128 VGPRs
  #pragma unroll
  for (int k0 = 0; k0 < 4; ++k0)
    #pragma unroll
    for (int nf = 0; nf < 8; ++nf) {
      const int e    = nf * 16 + l15;
      const int dcol = k0 * 32 + quad * 8;
      const int soff = e * 128 + (dcol ^ ((e & 7) << 3));
      zfr[k0][nf] = *(const bf16x8*)&sZ[soff];
    }

  const int b0 = split * 256;
  for (int bt = 0; bt < 2; ++bt) {
    const int rowbase = b0 + bt * 128 + w * 32;   // wave's 32 b-rows

    floatx4 acc[2][8];
    #pragma unroll
    for (int mf = 0; mf < 2; ++mf)
      #pragma unroll
      for (int nf = 0; nf < 8; ++nf)
        acc[mf][nf] = (floatx4){0.f, 0.f, 0.f, 0.f};

    #pragma unroll
    for (int mf = 0; mf < 2; ++mf) {
      // A-frags for this 16-row group: direct global bf16 loads (16B/lane)
      bf16x8 af[4];
      const unsigned short* ap =
          featB + (size_t)(rowbase + mf * 16 + l15) * FD + i * D_SZ + quad * 8;
      #pragma unroll
      for (int k0 = 0; k0 < 4; ++k0) af[k0] = *(const bf16x8*)(ap + k0 * 32);
      #pragma unroll
      for (int k0 = 0; k0 < 4; ++k0)
        #pragma unroll
        for (int nf = 0; nf < 8; ++nf)
          acc[mf][nf] = __builtin_amdgcn_mfma_f32_16x16x32_bf16(
              af[k0], zfr[k0][nf], acc[mf][nf], 0, 0, 0);
    }

    // ---- epilogue: out[b] = sum_e Y[b,e] * f_j[b,e] (f32 f_j, as before) ----
    // C/D layout (verified m89/m91): col = lane&15, row = quad*4 + reg
    #pragma unroll
    for (int mf = 0; mf < 2; ++mf) {
      float pl[4] = {0.f, 0.f, 0.f, 0.f};
      const int rb = rowbase + mf * 16 + quad * 4;   // global b-row of reg 0
      #pragma unroll
      for (int nf = 0; nf < 8; ++nf) {
        const int col = nf * 16 + l15;
        const float* fj = feat + (size_t)rb * FD + j * D_SZ + col;
        floatx4 c = acc[mf][nf];
        pl[0] += c[0] * fj[0];
        pl[1] += c[1] * fj[FD];
        pl[2] += c[2] * fj[2 * FD];
        pl[3] += c[3] * fj[3 * FD];
      }
      #pragma unroll
      for (int off = 1; off < 16; off <<= 1) {
        pl[0] += __shfl_xor(pl[0], off, 64);
        pl[1] += __shfl_xor(pl[1], off, 64);
        pl[2] += __shfl_xor(pl[2], off, 64);
        pl[3] += __shfl_xor(pl[3], off, 64);
      }
      if (l15 == 0) {
        size_t ob = (size_t)rb * (F_SZ * F_SZ) + (size_t)i * F_SZ + j;
        out[ob]                   = pl[0];
        out[ob + 1 * F_SZ * F_SZ] = pl[1];
        out[ob + 2 * F_SZ * F_SZ] = pl[2];
        out[ob + 3 * F_SZ * F_SZ] = pl[3];
      }
    }
  }
}

extern "C" void kernel_launch(void* const* d_in, const int* in_sizes, int n_in,
                              void* d_out, int out_size, void* d_ws, size_t ws_size,
                              hipStream_t stream) {
  const float* feat = (const float*)d_in[0];   // [B, F, D] fp32
  const float* mat  = (const float*)d_in[1];   // [F, F, D, D] fp32
  float* out = (float*)d_out;                  // [B, F, F] fp32

  unsigned short* featB = (unsigned short*)d_ws;                 // 8MB bf16 feature
  unsigned short* ZT    = featB + (size_t)B_SZ * F_SZ * D_SZ;    // 15.9MB bf16 Z^T

  // zero the whole output (diagonal + lower triangle stay 0)
  hipMemsetAsync(out, 0, (size_t)out_size * sizeof(float), stream);

  feat_cvt_kernel<<<dim3((B_SZ * F_SZ * D_SZ) / (256 * 8)), dim3(256), 0, stream>>>(feat, featB);
  z_prep_kernel<<<dim3(NPAIR), dim3(256), 0, stream>>>(mat, ZT);
  interaction_pair_kernel<<<dim3(NPAIR * 4), dim3(256), 0, stream>>>(feat, featB, ZT, out);
}